// Round 4
// baseline (270.129 us; speedup 1.0000x reference)
//
#include <hip/hip_runtime.h>
#include <math.h>

#define MN_EPS 1e-4f

typedef float v4f __attribute__((ext_vector_type(4)));  // for nontemporal builtin

__device__ inline void f4add(float4& a, const float4& b) {
    a.x += b.x; a.y += b.y; a.z += b.z; a.w += b.w;
}

// ---------------------------------------------------------------------------
// Kernel 1: per-block partial per-channel sums / sums-of-squares over a
// contiguous stripe of rows. Branchless: multiply by maskf (0/1) so every
// row-load is unconditional -> unroll-4 keeps 4 independent 16B loads in
// flight per wave (streaming BW instead of latency-bound). Also warms L3
// with the whole of y for the apply pass.
// ---------------------------------------------------------------------------
#define MN_CHUNK 256
__global__ void __launch_bounds__(256) mn_stats(
    const float4* __restrict__ y4, const int* __restrict__ mask,
    float4* __restrict__ pSum, float4* __restrict__ pSq,
    float* __restrict__ pCnt, int rowsPerBlock, int C4)
{
    __shared__ float sMaskF[MN_CHUNK];
    __shared__ float sCnt[256];
    const int tid = threadIdx.x;
    const int b = blockIdx.x;
    const long r0 = (long)b * rowsPerBlock;
    float4 s = make_float4(0.f, 0.f, 0.f, 0.f);
    float4 q = make_float4(0.f, 0.f, 0.f, 0.f);
    float lc = 0.f;  // each mask row staged by exactly one thread -> block sum = count
    for (int base = 0; base < rowsPerBlock; base += MN_CHUNK) {
        const int mrows = min(MN_CHUNK, rowsPerBlock - base);
        __syncthreads();  // protect sMaskF reuse
        for (int t = tid; t < mrows; t += 256) {
            const float mf = (mask[r0 + base + t] > 0) ? 1.0f : 0.0f;
            sMaskF[t] = mf;
            lc += mf;
        }
        __syncthreads();
        #pragma unroll 4
        for (int i = 0; i < mrows; ++i) {
            const float mf = sMaskF[i];
            const float4 v = y4[(r0 + base + i) * C4 + tid];
            const float4 mv = make_float4(mf * v.x, mf * v.y, mf * v.z, mf * v.w);
            s.x += mv.x; s.y += mv.y; s.z += mv.z; s.w += mv.w;
            q.x = fmaf(mv.x, v.x, q.x);
            q.y = fmaf(mv.y, v.y, q.y);
            q.z = fmaf(mv.z, v.z, q.z);
            q.w = fmaf(mv.w, v.w, q.w);
        }
    }
    pSum[(long)b * C4 + tid] = s;
    pSq [(long)b * C4 + tid] = q;
    sCnt[tid] = lc;
    __syncthreads();
    for (int off = 128; off > 0; off >>= 1) {
        if (tid < off) sCnt[tid] += sCnt[tid + off];
        __syncthreads();
    }
    if (tid == 0) pCnt[b] = sCnt[0];
}

// ---------------------------------------------------------------------------
// Kernel 2: one block per float4-of-channels (grid = C4). 256 threads stripe
// over the P partials, LDS tree-reduce, then thread 0 computes the fused
// affine coefficients a[c] = gamma/(std+eps), b[c] = beta - mean*a.
// ---------------------------------------------------------------------------
__global__ void __launch_bounds__(256) mn_finalize(
    const float4* __restrict__ pSum4, const float4* __restrict__ pSq4,
    const float* __restrict__ pCnt,
    const float4* __restrict__ gamma4, const float4* __restrict__ beta4,
    float4* __restrict__ aArr4, float4* __restrict__ bArr4, int P, int C4)
{
    __shared__ float4 sS[256];
    __shared__ float4 sQ[256];
    __shared__ float  sN[256];
    const int tid = threadIdx.x;
    const int c4 = blockIdx.x;

    float4 s = make_float4(0.f, 0.f, 0.f, 0.f);
    float4 q = make_float4(0.f, 0.f, 0.f, 0.f);
    float  n = 0.f;
    for (int p = tid; p < P; p += 256) {
        f4add(s, pSum4[(size_t)p * C4 + c4]);
        f4add(q, pSq4 [(size_t)p * C4 + c4]);
        n += pCnt[p];
    }
    sS[tid] = s; sQ[tid] = q; sN[tid] = n;
    __syncthreads();
    for (int off = 128; off > 0; off >>= 1) {
        if (tid < off) {
            f4add(sS[tid], sS[tid + off]);
            f4add(sQ[tid], sQ[tid + off]);
            sN[tid] += sN[tid + off];
        }
        __syncthreads();
    }
    if (tid == 0) {
        const float nn = sN[0];
        const float4 S = sS[0];
        const float4 Q = sQ[0];
        const float4 G = gamma4[c4];
        const float4 Bt = beta4[c4];
        float4 A, Bo;
        {
            const float mean = S.x / nn;
            float var = fmaxf((Q.x - S.x * S.x / nn) / (nn - 1.0f), 0.0f);
            A.x = G.x / (sqrtf(var) + MN_EPS);
            Bo.x = Bt.x - mean * A.x;
        }
        {
            const float mean = S.y / nn;
            float var = fmaxf((Q.y - S.y * S.y / nn) / (nn - 1.0f), 0.0f);
            A.y = G.y / (sqrtf(var) + MN_EPS);
            Bo.y = Bt.y - mean * A.y;
        }
        {
            const float mean = S.z / nn;
            float var = fmaxf((Q.z - S.z * S.z / nn) / (nn - 1.0f), 0.0f);
            A.z = G.z / (sqrtf(var) + MN_EPS);
            Bo.z = Bt.z - mean * A.z;
        }
        {
            const float mean = S.w / nn;
            float var = fmaxf((Q.w - S.w * S.w / nn) / (nn - 1.0f), 0.0f);
            A.w = G.w / (sqrtf(var) + MN_EPS);
            Bo.w = Bt.w - mean * A.w;
        }
        aArr4[c4] = A;
        bArr4[c4] = Bo;
    }
}

// ---------------------------------------------------------------------------
// Kernel 3: out[r][c] = mask[r] ? a[c]*y[r][c] + b[c] : y[r][c]
// Contiguous row tile per block (DRAM page locality), branchless select,
// unroll-2 for MLP, nontemporal stores (out never re-read; keep y in cache).
// ---------------------------------------------------------------------------
__global__ void __launch_bounds__(256) mn_apply(
    const float4* __restrict__ y4, const int* __restrict__ mask,
    const float4* __restrict__ aArr4, const float4* __restrict__ bArr4,
    float4* __restrict__ out4, int rowsPerBlock, int C4)
{
    const int tid = threadIdx.x;
    const float4 A  = aArr4[tid];
    const float4 Bv = bArr4[tid];
    const long r0 = (long)blockIdx.x * rowsPerBlock;
    #pragma unroll 2
    for (int i = 0; i < rowsPerBlock; ++i) {
        const long r = r0 + i;
        const bool m = mask[r] > 0;
        const float4 v = y4[r * C4 + tid];
        v4f o;
        o.x = m ? fmaf(A.x, v.x, Bv.x) : v.x;
        o.y = m ? fmaf(A.y, v.y, Bv.y) : v.y;
        o.z = m ? fmaf(A.z, v.z, Bv.z) : v.z;
        o.w = m ? fmaf(A.w, v.w, Bv.w) : v.w;
        __builtin_nontemporal_store(o, (v4f*)&out4[r * C4 + tid]);
    }
}

extern "C" void kernel_launch(void* const* d_in, const int* in_sizes, int n_in,
                              void* d_out, int out_size, void* d_ws, size_t ws_size,
                              hipStream_t stream)
{
    const float* y     = (const float*)d_in[0];
    const int*   mask  = (const int*)  d_in[1];
    const float* gamma = (const float*)d_in[2];
    const float* beta  = (const float*)d_in[3];
    float* out = (float*)d_out;

    const int R  = in_sizes[1];   // B*T (mask element count)
    const int C  = in_sizes[2];   // channels (gamma element count)
    const int C4 = C / 4;         // 256 for C=1024

    // Pick the largest partial-count P whose workspace fits.
    int P = 1024;
    while (P > 1) {
        const size_t need = ((size_t)2 * P * C + P + 2 * C) * sizeof(float);
        if (need <= ws_size && (R % P) == 0) break;
        P >>= 1;
    }
    const int rowsPerBlock = R / P;

    float* w    = (float*)d_ws;
    float* pSum = w;
    float* pSq  = pSum + (size_t)P * C;
    float* pCnt = pSq  + (size_t)P * C;
    float* aArr = pCnt + P;
    float* bArr = aArr + C;

    mn_stats<<<P, C4, 0, stream>>>((const float4*)y, mask,
                                   (float4*)pSum, (float4*)pSq, pCnt,
                                   rowsPerBlock, C4);

    mn_finalize<<<C4, 256, 0, stream>>>((const float4*)pSum, (const float4*)pSq,
                                        pCnt, (const float4*)gamma,
                                        (const float4*)beta,
                                        (float4*)aArr, (float4*)bArr, P, C4);

    // 8 rows per block -> 4096 blocks, contiguous tiles.
    int rpbA = 8;
    while ((R % rpbA) != 0 && rpbA > 1) rpbA >>= 1;
    mn_apply<<<R / rpbA, C4, 0, stream>>>((const float4*)y, mask,
                                          (const float4*)aArr, (const float4*)bArr,
                                          (float4*)out, rpbA, C4);
}

// Round 6
// 263.235 us; speedup vs baseline: 1.0262x; 1.0262x over previous
//
#include <hip/hip_runtime.h>
#include <math.h>

#define MN_EPS 1e-4f
#define MN_MAXRPB 64   // max rows per block in the stats stripe (R/G = 32 here)

__device__ inline void f4add(float4& a, const float4& b) {
    a.x += b.x; a.y += b.y; a.z += b.z; a.w += b.w;
}

// ---------------------------------------------------------------------------
// Kernel 1: per-block partial per-channel sum/sumsq over a 32-row stripe.
// Mask is staged and COMPACTED into an LDS index list of valid rows, so the
// accumulation loop issues unconditional, independent float4 loads over valid
// rows only: half the read traffic of branchless-all-rows, none of the
// latency serialization of a per-row conditional load.
// ---------------------------------------------------------------------------
__global__ void __launch_bounds__(256) mn_stats(
    const float4* __restrict__ y4, const int* __restrict__ mask,
    float4* __restrict__ pSum, float4* __restrict__ pSq,
    float* __restrict__ pCnt, int rowsPerBlock, int C4)
{
    __shared__ int sFlag[MN_MAXRPB];
    __shared__ int sIdx[MN_MAXRPB];
    __shared__ int sNum;
    const int tid = threadIdx.x;
    const int b = blockIdx.x;
    const long r0 = (long)b * rowsPerBlock;

    for (int t = tid; t < rowsPerBlock; t += 256)
        sFlag[t] = (mask[r0 + t] > 0) ? 1 : 0;
    __syncthreads();
    if (tid == 0) {
        int n = 0;
        for (int i = 0; i < rowsPerBlock; ++i)
            if (sFlag[i]) sIdx[n++] = i;
        sNum = n;
    }
    __syncthreads();
    const int nv = sNum;

    float4 s = make_float4(0.f, 0.f, 0.f, 0.f);
    float4 q = make_float4(0.f, 0.f, 0.f, 0.f);
    #pragma unroll 4
    for (int j = 0; j < nv; ++j) {
        const float4 v = y4[(r0 + sIdx[j]) * C4 + tid];
        s.x += v.x; s.y += v.y; s.z += v.z; s.w += v.w;
        q.x = fmaf(v.x, v.x, q.x);
        q.y = fmaf(v.y, v.y, q.y);
        q.z = fmaf(v.z, v.z, q.z);
        q.w = fmaf(v.w, v.w, q.w);
    }
    pSum[(long)b * C4 + tid] = s;
    pSq [(long)b * C4 + tid] = q;
    if (tid == 0) pCnt[b] = (float)nv;
}

// ---------------------------------------------------------------------------
// Kernel 2: one block per float4-of-channels (grid = C4). 256 threads stripe
// over the P partials, LDS tree-reduce, then thread 0 computes the fused
// affine coefficients a[c] = gamma/(std+eps), b[c] = beta - mean*a.
// ---------------------------------------------------------------------------
__global__ void __launch_bounds__(256) mn_finalize(
    const float4* __restrict__ pSum4, const float4* __restrict__ pSq4,
    const float* __restrict__ pCnt,
    const float4* __restrict__ gamma4, const float4* __restrict__ beta4,
    float4* __restrict__ aArr4, float4* __restrict__ bArr4, int P, int C4)
{
    __shared__ float4 sS[256];
    __shared__ float4 sQ[256];
    __shared__ float  sN[256];
    const int tid = threadIdx.x;
    const int c4 = blockIdx.x;

    float4 s = make_float4(0.f, 0.f, 0.f, 0.f);
    float4 q = make_float4(0.f, 0.f, 0.f, 0.f);
    float  n = 0.f;
    for (int p = tid; p < P; p += 256) {
        f4add(s, pSum4[(size_t)p * C4 + c4]);
        f4add(q, pSq4 [(size_t)p * C4 + c4]);
        n += pCnt[p];
    }
    sS[tid] = s; sQ[tid] = q; sN[tid] = n;
    __syncthreads();
    for (int off = 128; off > 0; off >>= 1) {
        if (tid < off) {
            f4add(sS[tid], sS[tid + off]);
            f4add(sQ[tid], sQ[tid + off]);
            sN[tid] += sN[tid + off];
        }
        __syncthreads();
    }
    if (tid == 0) {
        const float nn = sN[0];
        const float4 S = sS[0];
        const float4 Q = sQ[0];
        const float4 G = gamma4[c4];
        const float4 Bt = beta4[c4];
        float4 A, Bo;
        {
            const float mean = S.x / nn;
            const float var = fmaxf((Q.x - S.x * S.x / nn) / (nn - 1.0f), 0.0f);
            A.x = G.x / (sqrtf(var) + MN_EPS);
            Bo.x = Bt.x - mean * A.x;
        }
        {
            const float mean = S.y / nn;
            const float var = fmaxf((Q.y - S.y * S.y / nn) / (nn - 1.0f), 0.0f);
            A.y = G.y / (sqrtf(var) + MN_EPS);
            Bo.y = Bt.y - mean * A.y;
        }
        {
            const float mean = S.z / nn;
            const float var = fmaxf((Q.z - S.z * S.z / nn) / (nn - 1.0f), 0.0f);
            A.z = G.z / (sqrtf(var) + MN_EPS);
            Bo.z = Bt.z - mean * A.z;
        }
        {
            const float mean = S.w / nn;
            const float var = fmaxf((Q.w - S.w * S.w / nn) / (nn - 1.0f), 0.0f);
            A.w = G.w / (sqrtf(var) + MN_EPS);
            Bo.w = Bt.w - mean * A.w;
        }
        aArr4[c4] = A;
        bArr4[c4] = Bo;
    }
}

// ---------------------------------------------------------------------------
// Kernel 3 (R2-proven version): out[r][c] = mask[r] ? a[c]*y[r][c]+b[c] : y[r][c]
// Grid-stride over rows, a4/b4 loop-invariant in registers, plain stores.
// ---------------------------------------------------------------------------
__global__ void __launch_bounds__(256) mn_apply(
    const float4* __restrict__ y4, const int* __restrict__ mask,
    const float4* __restrict__ aArr4, const float4* __restrict__ bArr4,
    float4* __restrict__ out4, int R, int C4)
{
    const int tid = threadIdx.x;
    const float4 A = aArr4[tid];
    const float4 Bv = bArr4[tid];
    for (int r = blockIdx.x; r < R; r += gridDim.x) {
        const float4 v = y4[(long)r * C4 + tid];
        float4 o;
        if (mask[r] > 0) {
            o.x = fmaf(A.x, v.x, Bv.x);
            o.y = fmaf(A.y, v.y, Bv.y);
            o.z = fmaf(A.z, v.z, Bv.z);
            o.w = fmaf(A.w, v.w, Bv.w);
        } else {
            o = v;
        }
        out4[(long)r * C4 + tid] = o;
    }
}

extern "C" void kernel_launch(void* const* d_in, const int* in_sizes, int n_in,
                              void* d_out, int out_size, void* d_ws, size_t ws_size,
                              hipStream_t stream)
{
    const float* y     = (const float*)d_in[0];
    const int*   mask  = (const int*)  d_in[1];
    const float* gamma = (const float*)d_in[2];
    const float* beta  = (const float*)d_in[3];
    float* out = (float*)d_out;

    const int R  = in_sizes[1];   // B*T (mask element count)
    const int C  = in_sizes[2];   // channels (gamma element count)
    const int C4 = C / 4;         // 256 for C=1024

    // Largest P <= 1024 that divides R, keeps stripe <= MN_MAXRPB, fits ws.
    int P = 1024;
    while (P > 1) {
        const size_t need = ((size_t)2 * P * C + P + 2 * C) * sizeof(float);
        if (need <= ws_size && (R % P) == 0 && (R / P) <= MN_MAXRPB) break;
        P >>= 1;
    }
    const int rowsPerBlock = R / P;

    float* w    = (float*)d_ws;
    float* pSum = w;
    float* pSq  = pSum + (size_t)P * C;
    float* pCnt = pSq  + (size_t)P * C;
    float* aArr = pCnt + P;
    float* bArr = aArr + C;

    mn_stats<<<P, C4, 0, stream>>>((const float4*)y, mask,
                                   (float4*)pSum, (float4*)pSq, pCnt,
                                   rowsPerBlock, C4);

    mn_finalize<<<C4, 256, 0, stream>>>((const float4*)pSum, (const float4*)pSq,
                                        pCnt, (const float4*)gamma,
                                        (const float4*)beta,
                                        (float4*)aArr, (float4*)bArr, P, C4);

    mn_apply<<<2048, C4, 0, stream>>>((const float4*)y, mask,
                                      (const float4*)aArr, (const float4*)bArr,
                                      (float4*)out, R, C4);
}